// Round 16
// baseline (3114.880 us; speedup 1.0000x reference)
//
#include <hip/hip_runtime.h>

using u16 = unsigned short;
using u32 = unsigned int;
using bf16x8 = __attribute__((ext_vector_type(8))) __bf16;
using u16x8  = __attribute__((ext_vector_type(8))) u16;
using f32x4  = __attribute__((ext_vector_type(4))) float;
using u32x4  = __attribute__((ext_vector_type(4))) u32;

#define SEQ    2048
#define BATCH  2
#define DIM    1024
#define HEADS  16
#define HD     64
#define FF     4096
#define LAYERS 4
#define VOCAB  32000
#define ROWS   (BATCH*SEQ)   // 4096

__device__ __forceinline__ u16 f2bf(float f) {
  u32 u = __float_as_uint(f);
  u += 0x7fffu + ((u >> 16) & 1u);
  return (u16)(u >> 16);
}
__device__ __forceinline__ float bf2f(u16 h) { return __uint_as_float(((u32)h) << 16); }

__device__ __forceinline__ void gload_lds16(const u16* g, u16* l) {
  __builtin_amdgcn_global_load_lds(
      (__attribute__((address_space(1))) void*)(u16*)g,
      (__attribute__((address_space(3))) void*)l, 16, 0, 0);
}

// ================= 128x128 GEMM, double-buffered =============================
// C[M,N] = A[M,K] * B[N,K]^T; EPI 1: f32 += (residual)  EPI 5: f32 partial out
constexpr int BM = 128, BN = 128, BK = 32;

template<int EPI>
__global__ __launch_bounds__(256)
void gemm_nt(const u16* __restrict__ A, const u16* __restrict__ Bw,
             float* __restrict__ Cf, u16* __restrict__ Cb,
             int M, int N, int K, int KH)
{
  __shared__ __align__(16) u16 As[2][BM*BK];   // 2 x 8 KB
  __shared__ __align__(16) u16 Bs[2][BN*BK];   // 2 x 8 KB
  const int tid  = threadIdx.x;
  const int wid  = tid >> 6;
  const int lane = tid & 63;
  const int bn = blockIdx.x, bm = blockIdx.y;
  const int wm = wid >> 1, wn = wid & 1;    // 2x2 waves, 64x64 each

  // split-K: block z covers K-slice [z*KH, (z+1)*KH), writes partial z
  if constexpr (EPI == 5) {
    const int z = blockIdx.z;
    A  += (size_t)z * KH;
    Bw += (size_t)z * KH;
    Cf += (size_t)z * M * N;
  }

  f32x4 acc[4][4] = {};

  const int lr = lane >> 2;          // row within chunk
  const int lk = (lane & 3) * 8;     // k offset (bf16 elems)
  const u16* Ag0 = A  + (size_t)(bm*BM + wid*16     + lr)*K + lk;
  const u16* Ag1 = A  + (size_t)(bm*BM + (wid+4)*16 + lr)*K + lk;
  const u16* Bg0 = Bw + (size_t)(bn*BN + wid*16     + lr)*K + lk;
  const u16* Bg1 = Bw + (size_t)(bn*BN + (wid+4)*16 + lr)*K + lk;

  auto STG = [&](int buf, int k0) {
    gload_lds16(Ag0 + k0, &As[buf][ wid   *512]);
    gload_lds16(Ag1 + k0, &As[buf][(wid+4)*512]);
    gload_lds16(Bg0 + k0, &Bs[buf][ wid   *512]);
    gload_lds16(Bg1 + k0, &Bs[buf][(wid+4)*512]);
  };

  const int aoff = (wm*64 + (lane & 15))*BK + (lane >> 4)*8;
  const int boff = (wn*64 + (lane & 15))*BK + (lane >> 4)*8;

  STG(0, 0);
  const int nt = KH / BK;
  for (int t = 0; t < nt; ++t) {
    __syncthreads();                     // stage(t) landed; prev reads done
    if (t + 1 < nt) STG((t+1) & 1, (t+1)*BK);
    const u16* Asf = &As[t & 1][aoff];
    const u16* Bsf = &Bs[t & 1][boff];
    bf16x8 af[4], bfr[4];
    #pragma unroll
    for (int m = 0; m < 4; ++m) af[m] = *(const bf16x8*)(Asf + m*16*BK);
    #pragma unroll
    for (int n = 0; n < 4; ++n) bfr[n] = *(const bf16x8*)(Bsf + n*16*BK);
    #pragma unroll
    for (int m = 0; m < 4; ++m)
      #pragma unroll
      for (int n = 0; n < 4; ++n)
        acc[m][n] = __builtin_amdgcn_mfma_f32_16x16x32_bf16(af[m], bfr[n], acc[m][n], 0, 0, 0);
  }

  const int row0 = bm*BM + wm*64 + (lane >> 4)*4;
  const int col0 = bn*BN + wn*64 + (lane & 15);
  #pragma unroll
  for (int m = 0; m < 4; ++m) {
    #pragma unroll
    for (int n = 0; n < 4; ++n) {
      #pragma unroll
      for (int r = 0; r < 4; ++r) {
        const size_t idx = (size_t)(row0 + m*16 + r)*N + (col0 + n*16);
        const float v = acc[m][n][r];
        if constexpr (EPI == 0)      Cf[idx] = v;
        else if constexpr (EPI == 1) Cf[idx] += v;
        else if constexpr (EPI == 2) Cb[idx] = f2bf(v / (1.f + __expf(-v)));
        else if constexpr (EPI == 5) Cf[idx] = v;       // partial
        else                         Cb[idx] = f2bf(v);
      }
    }
  }
}

// x += p0 + p1, then RMSNorm(row) -> hbf. One row per block (256 thr x f4).
__global__ __launch_bounds__(256)
void residual_add2_norm(float* __restrict__ x, const float* __restrict__ p0,
                        const float* __restrict__ p1,
                        const float* __restrict__ scale, u16* __restrict__ out)
{
  const int row = blockIdx.x, t = threadIdx.x;
  const size_t i = (size_t)row*(DIM/4) + t;
  float4 a = ((const float4*)x)[i];
  const float4 b = ((const float4*)p0)[i];
  const float4 c = ((const float4*)p1)[i];
  a.x += b.x + c.x;
  a.y += b.y + c.y;
  a.z += b.z + c.z;
  a.w += b.w + c.w;
  ((float4*)x)[i] = a;
  float ss = a.x*a.x + a.y*a.y + a.z*a.z + a.w*a.w;
  #pragma unroll
  for (int off = 32; off; off >>= 1) ss += __shfl_xor(ss, off);
  __shared__ float red[4];
  if ((t & 63) == 0) red[t >> 6] = ss;
  __syncthreads();
  const float tot = red[0] + red[1] + red[2] + red[3];
  const float r = rsqrtf(tot * (1.f/(float)DIM) + 1e-6f);
  const float4 sc = ((const float4*)scale)[t];
  ushort4 o;
  o.x = f2bf(a.x * r * sc.x);
  o.y = f2bf(a.y * r * sc.y);
  o.z = f2bf(a.z * r * sc.z);
  o.w = f2bf(a.w * r * sc.w);
  ((ushort4*)(out + (size_t)row*DIM))[t] = o;
}

// ================= 256x256 8-phase GEMM (R4-exact loop) ======================
// EPI 2: bf16 silu (fc1)  4: fused rope/cvt qkv out
#define GPHASE(buf, q, STAGE_STMT, WAITV)                                     \
  {                                                                           \
    if ((q) == 0) {                                                           \
      _Pragma("unroll") for (int n = 0; n < 4; ++n)                           \
        _Pragma("unroll") for (int ks = 0; ks < 2; ++ks)                      \
          bfrag[n][ks] = ldsB((buf), wn*64 + n*16, ks);                       \
    }                                                                         \
    bf16x8 afrag[2][2];                                                       \
    _Pragma("unroll") for (int mi = 0; mi < 2; ++mi)                          \
      _Pragma("unroll") for (int ks = 0; ks < 2; ++ks)                        \
        afrag[mi][ks] = ldsA((buf), wm*128 + (q)*32 + mi*16, ks);             \
    STAGE_STMT;                                                               \
    __builtin_amdgcn_s_barrier();                                             \
    asm volatile("" ::: "memory");                                            \
    __builtin_amdgcn_s_setprio(1);                                            \
    _Pragma("unroll") for (int mi = 0; mi < 2; ++mi)                          \
      _Pragma("unroll") for (int n = 0; n < 4; ++n)                           \
        _Pragma("unroll") for (int ks = 0; ks < 2; ++ks)                      \
          acc[(q)*2+mi][n] = __builtin_amdgcn_mfma_f32_16x16x32_bf16(         \
              afrag[mi][ks], bfrag[n][ks], acc[(q)*2+mi][n], 0, 0, 0);        \
    __builtin_amdgcn_s_setprio(0);                                            \
    if ((WAITV) == 1) asm volatile("s_waitcnt vmcnt(6)" ::: "memory");        \
    if ((WAITV) == 2) asm volatile("s_waitcnt vmcnt(0)" ::: "memory");        \
    __builtin_amdgcn_s_barrier();                                             \
    asm volatile("" ::: "memory");                                            \
  }

template<int EPI>
__global__ __launch_bounds__(512, 2)
void gemm_nt_256(const u16* __restrict__ A, const u16* __restrict__ Bw,
                 float* __restrict__ Cf, u16* __restrict__ Cb,
                 u16* __restrict__ qbo, u16* __restrict__ kbo,
                 u16* __restrict__ vto, const float* __restrict__ tab,
                 int M, int N, int K, int nbm)
{
  __shared__ __align__(16) u16 lds[2][2][256*64];   // [buf][A=0,B=1] 128 KB
  const int tid = threadIdx.x, wid = tid >> 6, lane = tid & 63;
  // T1: XCD swizzle (all grids %8==0), bm fastest
  const int nwg = gridDim.x;
  const int swz = (blockIdx.x & 7)*(nwg >> 3) + (blockIdx.x >> 3);
  const int bm = swz % nbm, bn = swz / nbm;
  const int wm = wid >> 2, wn = wid & 3;            // 2x4 waves, 128x64 each

  f32x4 acc[8][4] = {};

  // ---- staging (pre-swizzled global source; linear gload_lds dest) ----
  const int lrow = lane >> 3;                        // 0..7
  const int lkel = ((lane & 7) ^ lrow) * 8;          // swizzled k elem offset
  const u16* Abase = A  + (size_t)(bm*256)*K + lkel;
  const u16* Bbase = Bw + (size_t)(bn*256)*K + lkel;
  auto stageA = [&](int buf, int ha, int t) {
    const int r0 = ha*64 + 8*wid, r1 = 128 + ha*64 + 8*wid;
    const size_t ko = (size_t)t*64;
    gload_lds16(Abase + (size_t)(r0 + lrow)*K + ko, &lds[buf][0][r0*64]);
    gload_lds16(Abase + (size_t)(r1 + lrow)*K + ko, &lds[buf][0][r1*64]);
  };
  auto stageB = [&](int buf, int hb, int t) {
    const int r0 = hb*128 + 8*wid, r1 = hb*128 + 64 + 8*wid;
    const size_t ko = (size_t)t*64;
    gload_lds16(Bbase + (size_t)(r0 + lrow)*K + ko, &lds[buf][1][r0*64]);
    gload_lds16(Bbase + (size_t)(r1 + lrow)*K + ko, &lds[buf][1][r1*64]);
  };

  // ---- fragment reads (swizzled) ----
  const int frow = lane & 15, g = lane >> 4;
  auto ldsA = [&](int buf, int rowbase, int ks) -> bf16x8 {
    return *(const bf16x8*)&lds[buf][0][(rowbase + frow)*64 + ((ks*4 + g) ^ (lane & 7))*8];
  };
  auto ldsB = [&](int buf, int rowbase, int ks) -> bf16x8 {
    return *(const bf16x8*)&lds[buf][1][(rowbase + frow)*64 + ((ks*4 + g) ^ (lane & 7))*8];
  };

  bf16x8 bfrag[4][2];
  const int NT = K / 64;   // even (>=16 for all our shapes)

  // prologue: tile0 fully + tile1 {B-lo,B-hi,A-h1}; wait tile0 (3 HT in flight)
  stageB(0,0,0); stageB(0,1,0); stageA(0,0,0); stageA(0,1,0);
  stageB(1,0,1); stageB(1,1,1); stageA(1,0,1);
  asm volatile("s_waitcnt vmcnt(6)" ::: "memory");
  __builtin_amdgcn_s_barrier();
  asm volatile("" ::: "memory");

  for (int i = 0; i < NT/2 - 1; ++i) {
    const int t0 = 2*i;
    GPHASE(0, 0, stageA(1,1,t0+1), 0)   // complete tile t0+1
    GPHASE(0, 1, stageB(0,0,t0+2), 0)
    GPHASE(0, 2, stageB(0,1,t0+2), 0)
    GPHASE(0, 3, stageA(0,0,t0+2), 1)   // vmcnt(6): tile t0+1 landed
    GPHASE(1, 0, stageA(0,1,t0+2), 0)   // complete tile t0+2
    GPHASE(1, 1, stageB(1,0,t0+3), 0)
    GPHASE(1, 2, stageB(1,1,t0+3), 0)
    GPHASE(1, 3, stageA(1,0,t0+3), 1)   // vmcnt(6): tile t0+2 landed
  }
  // peeled last iteration (t0 = NT-2): no further stages; one vmcnt(0) drain
  GPHASE(0, 0, stageA(1,1,NT-1), 0)
  GPHASE(0, 1, ((void)0), 0)
  GPHASE(0, 2, ((void)0), 0)
  GPHASE(0, 3, ((void)0), 2)            // vmcnt(0): tile NT-1 landed
  GPHASE(1, 0, ((void)0), 0)
  GPHASE(1, 1, ((void)0), 0)
  GPHASE(1, 2, ((void)0), 0)
  GPHASE(1, 3, ((void)0), 0)

  // ---- epilogue ----
  if constexpr (EPI == 4) {
    // Fused RoPE + bf16 cvt + V transpose (R9-verified).
    const int hc = bn*4 + wn;                 // head-chunk 0..47
    const int which = hc >> 4, h = hc & 15;   // 0=q 1=k 2=v
    const int brow0 = bm*256 + wm*128 + g*4;
    const int b = brow0 >> 11;                // block-uniform
    const int bh = b*HEADS + h;
    if (which == 2) {
      #pragma unroll
      for (int mrep = 0; mrep < 8; ++mrep) {
        const int s = (brow0 + mrep*16) & (SEQ-1);
        #pragma unroll
        for (int n = 0; n < 4; ++n) {
          const int d = frow + n*16;
          ushort4 pk;
          pk.x = f2bf(acc[mrep][n][0]); pk.y = f2bf(acc[mrep][n][1]);
          pk.z = f2bf(acc[mrep][n][2]); pk.w = f2bf(acc[mrep][n][3]);
          *(ushort4*)&vto[((size_t)bh*64 + d)*SEQ + s] = pk;
        }
      }
    } else {
      u16* outb = (which == 0) ? qbo : kbo;
      const float qs = (which == 0) ? 0.125f : 1.f;   // fold 1/sqrt(HD)
      #pragma unroll
      for (int mrep = 0; mrep < 8; ++mrep) {
        #pragma unroll
        for (int rr = 0; rr < 4; ++rr) {
          const int s = (brow0 + mrep*16 + rr) & (SEQ-1);
          const float c0 = tab[s*64 + frow],      s0v = tab[s*64 + 32 + frow];
          const float c1 = tab[s*64 + 16 + frow], s1v = tab[s*64 + 48 + frow];
          const float x0 = acc[mrep][0][rr], x1 = acc[mrep][1][rr];
          const float x2 = acc[mrep][2][rr], x3 = acc[mrep][3][rr];
          u16* orow = outb + ((size_t)bh*SEQ + s)*64;
          orow[frow]      = f2bf((x0*c0 - x2*s0v)*qs);
          orow[frow + 32] = f2bf((x2*c0 + x0*s0v)*qs);
          orow[frow + 16] = f2bf((x1*c1 - x3*s1v)*qs);
          orow[frow + 48] = f2bf((x3*c1 + x1*s1v)*qs);
        }
      }
    }
  } else {
    const int row0 = bm*256 + wm*128 + g*4;
    const int col0 = bn*256 + wn*64 + frow;
    #pragma unroll
    for (int mrep = 0; mrep < 8; ++mrep) {
      #pragma unroll
      for (int n = 0; n < 4; ++n) {
        #pragma unroll
        for (int r = 0; r < 4; ++r) {
          const size_t idx = (size_t)(row0 + mrep*16 + r)*N + (col0 + n*16);
          const float v = acc[mrep][n][r];
          if constexpr (EPI == 0)      Cf[idx] = v;
          else if constexpr (EPI == 2) Cb[idx] = f2bf(v / (1.f + __expf(-v)));
        }
      }
    }
  }
}

// ====== 256x256 single-buffer BK=64 GEMM (64 KB LDS -> 2 blocks/CU) ==========
// LM head only (grid 2000 >> 256 CUs; co-resident blocks hide staging stalls).
// Proven 2-__syncthreads pattern (compiler-managed vmcnt drains); identical
// both-sides swizzle mapping to gemm_nt_256. f32 scattered-store epilogue.
__global__ __launch_bounds__(512, 4)
void gemm_nt_256sb(const u16* __restrict__ A, const u16* __restrict__ Bw,
                   float* __restrict__ Cf, int M, int N, int K, int nbm)
{
  __shared__ __align__(16) u16 lds[2][256*64];   // [A=0,B=1] 64 KB
  const int tid = threadIdx.x, wid = tid >> 6, lane = tid & 63;
  const int nwg = gridDim.x;
  const int swz = (blockIdx.x & 7)*(nwg >> 3) + (blockIdx.x >> 3);
  const int bm = swz % nbm, bn = swz / nbm;
  const int wm = wid >> 2, wn = wid & 3;         // 2x4 waves, 128x64 each

  f32x4 acc[8][4] = {};

  const int lrow = lane >> 3;
  const int lkel = ((lane & 7) ^ lrow) * 8;      // pre-swizzled source slot
  const u16* Abase = A  + (size_t)(bm*256)*K + lkel;
  const u16* Bbase = Bw + (size_t)(bn*256)*K + lkel;

  auto STAGE = [&](int t) {                      // full 256x64 A and B tiles
    const size_t ko = (size_t)t*64;
    #pragma unroll
    for (int ha = 0; ha < 4; ++ha) {
      const int r = ha*64 + 8*wid;
      gload_lds16(Abase + (size_t)(r + lrow)*K + ko, &lds[0][r*64]);
      gload_lds16(Bbase + (size_t)(r + lrow)*K + ko, &lds[1][r*64]);
    }
  };

  const int frow = lane & 15, g = lane >> 4;
  auto ldsRD = [&](int ab, int rowbase, int ks) -> bf16x8 {
    return *(const bf16x8*)&lds[ab][(rowbase + frow)*64 + ((ks*4 + g) ^ (lane & 7))*8];
  };

  const int NT = K / 64;
  for (int t = 0; t < NT; ++t) {
    __syncthreads();                 // prev compute done reading buffer
    STAGE(t);
    __syncthreads();                 // stage landed (vmcnt drained by barrier)
    bf16x8 bfrag[4][2];
    #pragma unroll
    for (int n = 0; n < 4; ++n)
      #pragma unroll
      for (int ks = 0; ks < 2; ++ks)
        bfrag[n][ks] = ldsRD(1, wn*64 + n*16, ks);
    #pragma unroll
    for (int mrep = 0; mrep < 8; ++mrep) {
      bf16x8 af[2];
      af[0] = ldsRD(0, wm*128 + mrep*16, 0);
      af[1] = ldsRD(0, wm*128 + mrep*16, 1);
      #pragma unroll
      for (int n = 0; n < 4; ++n) {
        acc[mrep][n] = __builtin_amdgcn_mfma_f32_16x16x32_bf16(af[0], bfrag[n][0], acc[mrep][n], 0, 0, 0);
        acc[mrep][n] = __builtin_amdgcn_mfma_f32_16x16x32_bf16(af[1], bfrag[n][1], acc[mrep][n], 0, 0, 0);
      }
    }
  }

  const int row0 = bm*256 + wm*128 + g*4;
  const int col0 = bn*256 + wn*64 + frow;
  #pragma unroll
  for (int mrep = 0; mrep < 8; ++mrep)
    #pragma unroll
    for (int n = 0; n < 4; ++n)
      #pragma unroll
      for (int r = 0; r < 4; ++r)
        Cf[(size_t)(row0 + mrep*16 + r)*N + (col0 + n*16)] = acc[mrep][n][r];
}

// ---------------- elementwise / small kernels -------------------------------
__global__ void cvt_f32_bf16(const float* __restrict__ in, u16* __restrict__ out, int n4)
{
  const int i = blockIdx.x*256 + threadIdx.x;
  if (i >= n4) return;
  const float4 v = ((const float4*)in)[i];
  ushort4 o;
  o.x = f2bf(v.x); o.y = f2bf(v.y); o.z = f2bf(v.z); o.w = f2bf(v.w);
  ((ushort4*)out)[i] = o;
}

// all 4 per-layer weight conversions in one launch
__global__ void cvt_layer(const float* __restrict__ qw, const float* __restrict__ ow,
                          const float* __restrict__ f1, const float* __restrict__ f2,
                          u16* __restrict__ wq, u16* __restrict__ wo,
                          u16* __restrict__ w1, u16* __restrict__ w2)
{
  int i = blockIdx.x*256 + threadIdx.x;   // total 3.146M float4 groups
  const float* src; u16* dst;
  if (i < 786432)       { src = qw; dst = wq; }
  else if (i < 1048576) { src = ow; dst = wo; i -= 786432; }
  else if (i < 2097152) { src = f1; dst = w1; i -= 1048576; }
  else                  { src = f2; dst = w2; i -= 2097152; }
  const float4 v = ((const float4*)src)[i];
  ushort4 o;
  o.x = f2bf(v.x); o.y = f2bf(v.y); o.z = f2bf(v.z); o.w = f2bf(v.w);
  ((ushort4*)dst)[i] = o;
}

__global__ void embed_gather(const int* __restrict__ ids, const float* __restrict__ emb,
                             float* __restrict__ x)
{
  const int row = blockIdx.x, t = threadIdx.x;
  const int id = ids[row];
  ((float4*)(x + (size_t)row*DIM))[t] = ((const float4*)(emb + (size_t)id*DIM))[t];
}

__global__ __launch_bounds__(256)
void rmsnorm_bf16(const float* __restrict__ x, const float* __restrict__ scale,
                  u16* __restrict__ out)
{
  const int row = blockIdx.x, t = threadIdx.x;
  const float4 v = ((const float4*)(x + (size_t)row*DIM))[t];
  float ss = v.x*v.x + v.y*v.y + v.z*v.z + v.w*v.w;
  #pragma unroll
  for (int off = 32; off; off >>= 1) ss += __shfl_xor(ss, off);
  __shared__ float red[4];
  if ((t & 63) == 0) red[t >> 6] = ss;
  __syncthreads();
  const float tot = red[0] + red[1] + red[2] + red[3];
  const float r = rsqrtf(tot * (1.f/(float)DIM) + 1e-6f);
  const float4 sc = ((const float4*)scale)[t];
  ushort4 o;
  o.x = f2bf(v.x * r * sc.x);
  o.y = f2bf(v.y * r * sc.y);
  o.z = f2bf(v.z * r * sc.z);
  o.w = f2bf(v.w * r * sc.w);
  ((ushort4*)(out + (size_t)row*DIM))[t] = o;
}

__global__ void rope_table(float* __restrict__ tab)
{
  const int idx = blockIdx.x*256 + threadIdx.x;  // SEQ*32 threads
  const int s = idx >> 5, i = idx & 31;
  const float invf = powf(10000.f, -(float)i/32.f);
  const float f = (float)s * invf;
  tab[s*64 + i]      = cosf(f);
  tab[s*64 + 32 + i] = sinf(f);
}

// ---------------- MFMA flash attention: 64-key iterations (R13-exact) --------
__global__ __launch_bounds__(256, 4)
void attn_fwd(const u16* __restrict__ qb, const u16* __restrict__ kb,
              const u16* __restrict__ vt, u16* __restrict__ ctx)
{
  const int wid = threadIdx.x >> 6, lane = threadIdx.x & 63;
  const int bh = blockIdx.x >> 5, j = blockIdx.x & 31;
  const int qt = (wid == 0) ? j : (wid == 1) ? 63 - j : (wid == 2) ? 64 + j : 127 - j;
  const int q0 = qt * 16;
  const int g = lane >> 4, c15 = lane & 15;

  const u16* qbase = qb + (size_t)bh*SEQ*64;
  const u16* kbase = kb + (size_t)bh*SEQ*64;
  const u16* vtb   = vt + (size_t)bh*64*SEQ;

  const bf16x8 bQ0 = *(const bf16x8*)(qbase + (size_t)(q0 + c15)*64 + g*8);
  const bf16x8 bQ1 = *(const bf16x8*)(qbase + (size_t)(q0 + c15)*64 + 32 + g*8);

  f32x4 o[4] = {};
  float m = -INFINITY, lsum = 0.f;
  const int q_abs = q0 + c15;
  const int nt32 = (q0 >> 5) + 1;

  auto mk_aP = [&](const float* p) -> bf16x8 {
    const u32 pk00 = (u32)f2bf(p[0]) | ((u32)f2bf(p[1]) << 16);
    const u32 pk01 = (u32)f2bf(p[2]) | ((u32)f2bf(p[3]) << 16);
    const u32 pk10 = (u32)f2bf(p[4]) | ((u32)f2bf(p[5]) << 16);
    const u32 pk11 = (u32)f2bf(p[6]) | ((u32)f2bf(p[7]) << 16);
    u32 w[4];
    #pragma unroll
    for (int wi = 0; wi < 4; ++wi) {
      const int src = c15 | ((((g << 1) + (wi >> 1)) & 3) << 4);
      const u32 a0 = __shfl((wi & 1) ? pk01 : pk00, src);
      const u32 a1 = __shfl((wi & 1) ? pk11 : pk10, src);
      w[wi] = (g < 2) ? a0 : a1;
    }
    return __builtin_bit_cast(bf16x8, (u32x4){w[0], w[1], w[2], w[3]});
  };

  for (int t = 0; t < nt32; t += 2) {
    const int k0 = t*32;
    const bool haveB = (t + 1 < nt32);
    const bool diagA = (t     == nt32 - 1);
    const bool diagB = (t + 1 == nt32 - 1);

    const u16* kr0 = kbase + (size_t)(k0 + c15)*64 + g*8;
    const u16* kr1 = kbase + (size_t)(k0 + 16 + c15)*64 + g*8;
    const bf16x8 aK00 = *(const bf16x8*)(kr0);
    const bf16x8 aK01 = *(const bf16x8*)(kr0 + 32);
    const bf16x8 aK10 = *(const bf16x8*)(kr1);
    const bf16x8 aK11 = *(const bf16x8*)(kr1 + 32);
    bf16x8 aK20{}, aK21{}, aK30{}, aK31{};
    if (haveB) {
      const u16* kr2 = kbase + (size_t)(k0 + 32 + c15)*64 + g*8;
      const u16* kr3 = kbase + (size_t)(k0 + 48 + c15)*64 + g*8;
      aK20 = *(const bf16x8*)(kr2);
      aK21 = *(const bf16x8*)(kr2 + 32);
      aK30 = *(const bf16x8*)(kr3);
      aK31 = *(const bf16x8*)(kr3 + 32);
    }
    bf16x8 vvA[4];
    #pragma unroll
    for (int dh = 0; dh < 4; ++dh)
      vvA[dh] = *(const bf16x8*)(vtb + (size_t)(dh*16 + c15)*SEQ + k0 + g*8);

    const f32x4 z = {};
    f32x4 sc0 = __builtin_amdgcn_mfma_f32_16x16x32_bf16(aK00, bQ0, z, 0,0,0);
    sc0 = __builtin_amdgcn_mfma_f32_16x16x32_bf16(aK01, bQ1, sc0, 0,0,0);
    f32x4 sc1 = __builtin_amdgcn_mfma_f32_16x16x32_bf16(aK10, bQ0, z, 0,0,0);
    sc1 = __builtin_amdgcn_mfma_f32_16x16x32_bf16(aK11, bQ1, sc1, 0,0,0);
    f32x4 sc2 = z, sc3 = z;
    if (haveB) {
      sc2 = __builtin_amdgcn_mfma_f32_16x16x32_bf16(aK20, bQ0, z, 0,0,0);
      sc2 = __builtin_amdgcn_mfma_f32_16x16x32_bf16(aK21, bQ1, sc2, 0,0,0);
      sc3 = __builtin_amdgcn_mfma_f32_16x16x32_bf16(aK30, bQ0, z, 0,0,0);
      sc3 = __builtin_amdgcn_mfma_f32_16x16x32_bf16(aK31, bQ1, sc3, 0,0,0);
    }
    bf16x8 vvB[4] = {};
    if (haveB) {
      #pragma unroll
      for (int dh = 0; dh < 4; ++dh)
        vvB[dh] = *(const bf16x8*)(vtb + (size_t)(dh*16 + c15)*SEQ + k0 + 32 + g*8);
    }

    float s[16];
    if (diagA) {
      #pragma unroll
      for (int r = 0; r < 4; ++r) {
        s[r]   = (k0 + 4*g + r      > q_abs) ? -INFINITY : sc0[r];
        s[4+r] = (k0 + 16 + 4*g + r > q_abs) ? -INFINITY : sc1[r];
      }
    } else {
      #pragma unroll
      for (int r = 0; r < 4; ++r) { s[r] = sc0[r]; s[4+r] = sc1[r]; }
    }
    if (!haveB) {
      #pragma unroll
      for (int r = 0; r < 8; ++r) s[8+r] = -INFINITY;
    } else if (diagB) {
      #pragma unroll
      for (int r = 0; r < 4; ++r) {
        s[8+r]  = (k0 + 32 + 4*g + r > q_abs) ? -INFINITY : sc2[r];
        s[12+r] = (k0 + 48 + 4*g + r > q_abs) ? -INFINITY : sc3[r];
      }
    } else {
      #pragma unroll
      for (int r = 0; r < 4; ++r) { s[8+r] = sc2[r]; s[12+r] = sc3[r]; }
    }

    float tm = s[0];
    #pragma unroll
    for (int r = 1; r < 16; ++r) tm = fmaxf(tm, s[r]);
    tm = fmaxf(tm, __shfl_xor(tm, 16));
    tm = fmaxf(tm, __shfl_xor(tm, 32));

    if (!__all(tm <= m + 8.f)) {         // defer-max (T13)
      const float mnew = fmaxf(m, tm);
      const float corr = __expf(m - mnew);
      lsum *= corr;
      float corrq[4];
      #pragma unroll
      for (int r = 0; r < 4; ++r) corrq[r] = __shfl(corr, 4*g + r);
      #pragma unroll
      for (int dh = 0; dh < 4; ++dh)
        #pragma unroll
        for (int r = 0; r < 4; ++r) o[dh][r] *= corrq[r];
      m = mnew;
    }

    float p[16];
    #pragma unroll
    for (int r = 0; r < 16; ++r) p[r] = __expf(s[r] - m);
    float ps = 0.f;
    #pragma unroll
    for (int r = 0; r < 16; ++r) ps += p[r];
    ps += __shfl_xor(ps, 16);
    ps += __shfl_xor(ps, 32);
    lsum += ps;

    const bf16x8 aPA = mk_aP(&p[0]);
    #pragma unroll
    for (int dh = 0; dh < 4; ++dh)
      o[dh] = __builtin_amdgcn_mfma_f32_16x16x32_bf16(aPA, vvA[dh], o[dh], 0,0,0);
    if (haveB) {
      const bf16x8 aPB = mk_aP(&p[8]);
      #pragma unroll
      for (int dh = 0; dh < 4; ++dh)
        o[dh] = __builtin_amdgcn_mfma_f32_16x16x32_bf16(aPB, vvB[dh], o[dh], 0,0,0);
    }
  }

  float linv[4];
  #pragma unroll
  for (int r = 0; r < 4; ++r) linv[r] = 1.f / __shfl(lsum, 4*g + r);
  const int b = bh >> 4, h = bh & 15;
  #pragma unroll
  for (int r = 0; r < 4; ++r) {
    u16* crow = ctx + ((size_t)(b*SEQ + q0 + 4*g + r))*DIM + h*HD + c15;
    #pragma unroll
    for (int dh = 0; dh < 4; ++dh) crow[dh*16] = f2bf(o[dh][r] * linv[r]);
  }
}

// ---------------- host ------------------------------------------------------
extern "C" void kernel_launch(void* const* d_in, const int* in_sizes, int n_in,
                              void* d_out, int out_size, void* d_ws, size_t ws_size,
                              hipStream_t stream)
{
  const int*   ids   = (const int*)  d_in[0];
  const float* emb   = (const float*)d_in[1];
  const float* qkv_w = (const float*)d_in[2];
  const float* out_w = (const float*)d_in[3];
  const float* fc1_w = (const float*)d_in[4];
  const float* fc2_w = (const float*)d_in[5];
  const float* n1    = (const float*)d_in[6];
  const float* n2    = (const float*)d_in[7];
  const float* nf    = (const float*)d_in[8];
  const float* lm_w  = (const float*)d_in[9];
  float* logits = (float*)d_out;

  char* ws = (char*)d_ws;
  size_t off = 0;
  auto walloc = [&](size_t bytes) -> void* {
    void* p = ws + off;
    off += (bytes + 255) & ~(size_t)255;
    return p;
  };
  float* x     = (float*)walloc((size_t)ROWS*DIM*4);        // residual stream (f32)
  u16*   hbf   = (u16*)  walloc((size_t)ROWS*DIM*2);        // normed activ (bf16)
  u16*   ctxbf = (u16*)  walloc((size_t)ROWS*DIM*2);        // attn out (bf16)
  u16*   gbf   = (u16*)  walloc((size_t)ROWS*FF*2);         // silu(fc1) (bf16)
  u16*   wq    = (u16*)  walloc((size_t)3*DIM*DIM*2);
  u16*   wo    = (u16*)  walloc((size_t)DIM*DIM*2);
  u16*   w1    = (u16*)  walloc((size_t)FF*DIM*2);
  u16*   w2    = (u16*)  walloc((size_t)DIM*FF*2);
  float* tab   = (float*)walloc((size_t)SEQ*64*4);
  float* fpart = (float*)walloc((size_t)2*ROWS*DIM*4);      // split-K partials
  // bf16 Q/K/Vt alias gbf (25.2MB <= 33.6MB); lifetimes disjoint.
  u16* qbuf = (u16*)gbf;
  u16* kbuf = qbuf + (size_t)ROWS*DIM;
  u16* vtbuf= kbuf + (size_t)ROWS*DIM;
  // lm_w bf16 (65.5MB) aliases ctxbf..w2 (67.1MB) — all dead at LM-head time.
  u16* wlm = (u16*)ctxbf;

  rope_table<<<SEQ*32/256, 256, 0, stream>>>(tab);
  embed_gather<<<ROWS, 256, 0, stream>>>(ids, emb, x);
  rmsnorm_bf16<<<ROWS, 256, 0, stream>>>(x, n1, hbf);   // l=0 pre-attn norm

  for (int l = 0; l < LAYERS; ++l) {
    cvt_layer<<<3145728/256, 256, 0, stream>>>(
        qkv_w + (size_t)l*3*DIM*DIM, out_w + (size_t)l*DIM*DIM,
        fc1_w + (size_t)l*FF*DIM,    fc2_w + (size_t)l*DIM*FF,
        wq, wo, w1, w2);

    gemm_nt_256<4><<<(3*DIM/256)*(ROWS/256), 512, 0, stream>>>(
        hbf, wq, nullptr, nullptr, qbuf, kbuf, vtbuf, tab, ROWS, 3*DIM, DIM, ROWS/256);
    attn_fwd<<<BATCH*HEADS*(SEQ/64), 256, 0, stream>>>(qbuf, kbuf, vtbuf, ctxbf);
    // out-proj split-K=2 -> partials; fused reduce + residual + n2-norm
    gemm_nt<5><<<dim3(DIM/BN, ROWS/BM, 2), 256, 0, stream>>>(ctxbf, wo, fpart, nullptr, ROWS, DIM, DIM, DIM/2);
    residual_add2_norm<<<ROWS, 256, 0, stream>>>(x, fpart, fpart + (size_t)ROWS*DIM,
                                                 n2 + l*DIM, hbf);

    gemm_nt_256<2><<<(FF/256)*(ROWS/256), 512, 0, stream>>>(
        hbf, w1, nullptr, gbf, nullptr, nullptr, nullptr, nullptr, ROWS, FF, DIM, ROWS/256);
    // fc2 split-K=2 -> partials; fused reduce + residual + next-norm (n1 or nf)
    gemm_nt<5><<<dim3(DIM/BN, ROWS/BM, 2), 256, 0, stream>>>(gbf, w2, fpart, nullptr, ROWS, DIM, FF, FF/2);
    const float* nxt = (l < LAYERS-1) ? (n1 + (size_t)(l+1)*DIM) : nf;
    residual_add2_norm<<<ROWS, 256, 0, stream>>>(x, fpart, fpart + (size_t)ROWS*DIM,
                                                 nxt, hbf);
  }

  cvt_f32_bf16<<<VOCAB*DIM/4/256, 256, 0, stream>>>(lm_w, wlm, VOCAB*DIM/4);
  // LM head: single-buffer BK=64 variant (64 KB LDS -> 2 blocks/CU)
  gemm_nt_256sb<<<(VOCAB/256)*(ROWS/256), 512, 0, stream>>>(
      hbf, wlm, logits, ROWS, VOCAB, DIM, ROWS/256);
}

// Round 17
// 1597.361 us; speedup vs baseline: 1.9500x; 1.9500x over previous
//
#include <hip/hip_runtime.h>

using u16 = unsigned short;
using u32 = unsigned int;
using bf16x8 = __attribute__((ext_vector_type(8))) __bf16;
using u16x8  = __attribute__((ext_vector_type(8))) u16;
using f32x4  = __attribute__((ext_vector_type(4))) float;
using u32x4  = __attribute__((ext_vector_type(4))) u32;

#define SEQ    2048
#define BATCH  2
#define DIM    1024
#define HEADS  16
#define HD     64
#define FF     4096
#define LAYERS 4
#define VOCAB  32000
#define ROWS   (BATCH*SEQ)   // 4096

__device__ __forceinline__ u16 f2bf(float f) {
  u32 u = __float_as_uint(f);
  u += 0x7fffu + ((u >> 16) & 1u);
  return (u16)(u >> 16);
}
__device__ __forceinline__ float bf2f(u16 h) { return __uint_as_float(((u32)h) << 16); }

__device__ __forceinline__ void gload_lds16(const u16* g, u16* l) {
  __builtin_amdgcn_global_load_lds(
      (__attribute__((address_space(1))) void*)(u16*)g,
      (__attribute__((address_space(3))) void*)l, 16, 0, 0);
}

// ================= 128x128 GEMM, double-buffered =============================
// C[M,N] = A[M,K] * B[N,K]^T; EPI 1: f32 += (residual)  EPI 5: f32 partial out
constexpr int BM = 128, BN = 128, BK = 32;

template<int EPI>
__global__ __launch_bounds__(256)
void gemm_nt(const u16* __restrict__ A, const u16* __restrict__ Bw,
             float* __restrict__ Cf, u16* __restrict__ Cb,
             int M, int N, int K, int KH)
{
  __shared__ __align__(16) u16 As[2][BM*BK];   // 2 x 8 KB
  __shared__ __align__(16) u16 Bs[2][BN*BK];   // 2 x 8 KB
  const int tid  = threadIdx.x;
  const int wid  = tid >> 6;
  const int lane = tid & 63;
  const int bn = blockIdx.x, bm = blockIdx.y;
  const int wm = wid >> 1, wn = wid & 1;    // 2x2 waves, 64x64 each

  // split-K: block z covers K-slice [z*KH, (z+1)*KH), writes partial z
  if constexpr (EPI == 5) {
    const int z = blockIdx.z;
    A  += (size_t)z * KH;
    Bw += (size_t)z * KH;
    Cf += (size_t)z * M * N;
  }

  f32x4 acc[4][4] = {};

  const int lr = lane >> 2;          // row within chunk
  const int lk = (lane & 3) * 8;     // k offset (bf16 elems)
  const u16* Ag0 = A  + (size_t)(bm*BM + wid*16     + lr)*K + lk;
  const u16* Ag1 = A  + (size_t)(bm*BM + (wid+4)*16 + lr)*K + lk;
  const u16* Bg0 = Bw + (size_t)(bn*BN + wid*16     + lr)*K + lk;
  const u16* Bg1 = Bw + (size_t)(bn*BN + (wid+4)*16 + lr)*K + lk;

  auto STG = [&](int buf, int k0) {
    gload_lds16(Ag0 + k0, &As[buf][ wid   *512]);
    gload_lds16(Ag1 + k0, &As[buf][(wid+4)*512]);
    gload_lds16(Bg0 + k0, &Bs[buf][ wid   *512]);
    gload_lds16(Bg1 + k0, &Bs[buf][(wid+4)*512]);
  };

  const int aoff = (wm*64 + (lane & 15))*BK + (lane >> 4)*8;
  const int boff = (wn*64 + (lane & 15))*BK + (lane >> 4)*8;

  STG(0, 0);
  const int nt = KH / BK;
  for (int t = 0; t < nt; ++t) {
    __syncthreads();                     // stage(t) landed; prev reads done
    if (t + 1 < nt) STG((t+1) & 1, (t+1)*BK);
    const u16* Asf = &As[t & 1][aoff];
    const u16* Bsf = &Bs[t & 1][boff];
    bf16x8 af[4], bfr[4];
    #pragma unroll
    for (int m = 0; m < 4; ++m) af[m] = *(const bf16x8*)(Asf + m*16*BK);
    #pragma unroll
    for (int n = 0; n < 4; ++n) bfr[n] = *(const bf16x8*)(Bsf + n*16*BK);
    #pragma unroll
    for (int m = 0; m < 4; ++m)
      #pragma unroll
      for (int n = 0; n < 4; ++n)
        acc[m][n] = __builtin_amdgcn_mfma_f32_16x16x32_bf16(af[m], bfr[n], acc[m][n], 0, 0, 0);
  }

  const int row0 = bm*BM + wm*64 + (lane >> 4)*4;
  const int col0 = bn*BN + wn*64 + (lane & 15);
  #pragma unroll
  for (int m = 0; m < 4; ++m) {
    #pragma unroll
    for (int n = 0; n < 4; ++n) {
      #pragma unroll
      for (int r = 0; r < 4; ++r) {
        const size_t idx = (size_t)(row0 + m*16 + r)*N + (col0 + n*16);
        const float v = acc[m][n][r];
        if constexpr (EPI == 0)      Cf[idx] = v;
        else if constexpr (EPI == 1) Cf[idx] += v;
        else if constexpr (EPI == 2) Cb[idx] = f2bf(v / (1.f + __expf(-v)));
        else if constexpr (EPI == 5) Cf[idx] = v;       // partial
        else                         Cb[idx] = f2bf(v);
      }
    }
  }
}

// x += p0 + p1, then RMSNorm(row) -> hbf. One row per block (256 thr x f4).
__global__ __launch_bounds__(256)
void residual_add2_norm(float* __restrict__ x, const float* __restrict__ p0,
                        const float* __restrict__ p1,
                        const float* __restrict__ scale, u16* __restrict__ out)
{
  const int row = blockIdx.x, t = threadIdx.x;
  const size_t i = (size_t)row*(DIM/4) + t;
  float4 a = ((const float4*)x)[i];
  const float4 b = ((const float4*)p0)[i];
  const float4 c = ((const float4*)p1)[i];
  a.x += b.x + c.x;
  a.y += b.y + c.y;
  a.z += b.z + c.z;
  a.w += b.w + c.w;
  ((float4*)x)[i] = a;
  float ss = a.x*a.x + a.y*a.y + a.z*a.z + a.w*a.w;
  #pragma unroll
  for (int off = 32; off; off >>= 1) ss += __shfl_xor(ss, off);
  __shared__ float red[4];
  if ((t & 63) == 0) red[t >> 6] = ss;
  __syncthreads();
  const float tot = red[0] + red[1] + red[2] + red[3];
  const float r = rsqrtf(tot * (1.f/(float)DIM) + 1e-6f);
  const float4 sc = ((const float4*)scale)[t];
  ushort4 o;
  o.x = f2bf(a.x * r * sc.x);
  o.y = f2bf(a.y * r * sc.y);
  o.z = f2bf(a.z * r * sc.z);
  o.w = f2bf(a.w * r * sc.w);
  ((ushort4*)(out + (size_t)row*DIM))[t] = o;
}

// ================= 256x256 8-phase GEMM (R4-exact loop) ======================
// EPI 0: f32 out (LM head)  2: bf16 silu (fc1)  4: fused rope/cvt qkv out
#define GPHASE(buf, q, STAGE_STMT, WAITV)                                     \
  {                                                                           \
    if ((q) == 0) {                                                           \
      _Pragma("unroll") for (int n = 0; n < 4; ++n)                           \
        _Pragma("unroll") for (int ks = 0; ks < 2; ++ks)                      \
          bfrag[n][ks] = ldsB((buf), wn*64 + n*16, ks);                       \
    }                                                                         \
    bf16x8 afrag[2][2];                                                       \
    _Pragma("unroll") for (int mi = 0; mi < 2; ++mi)                          \
      _Pragma("unroll") for (int ks = 0; ks < 2; ++ks)                        \
        afrag[mi][ks] = ldsA((buf), wm*128 + (q)*32 + mi*16, ks);             \
    STAGE_STMT;                                                               \
    __builtin_amdgcn_s_barrier();                                             \
    asm volatile("" ::: "memory");                                            \
    __builtin_amdgcn_s_setprio(1);                                            \
    _Pragma("unroll") for (int mi = 0; mi < 2; ++mi)                          \
      _Pragma("unroll") for (int n = 0; n < 4; ++n)                           \
        _Pragma("unroll") for (int ks = 0; ks < 2; ++ks)                      \
          acc[(q)*2+mi][n] = __builtin_amdgcn_mfma_f32_16x16x32_bf16(         \
              afrag[mi][ks], bfrag[n][ks], acc[(q)*2+mi][n], 0, 0, 0);        \
    __builtin_amdgcn_s_setprio(0);                                            \
    if ((WAITV) == 1) asm volatile("s_waitcnt vmcnt(6)" ::: "memory");        \
    if ((WAITV) == 2) asm volatile("s_waitcnt vmcnt(0)" ::: "memory");        \
    __builtin_amdgcn_s_barrier();                                             \
    asm volatile("" ::: "memory");                                            \
  }

template<int EPI>
__global__ __launch_bounds__(512, 2)
void gemm_nt_256(const u16* __restrict__ A, const u16* __restrict__ Bw,
                 float* __restrict__ Cf, u16* __restrict__ Cb,
                 u16* __restrict__ qbo, u16* __restrict__ kbo,
                 u16* __restrict__ vto, const float* __restrict__ tab,
                 int M, int N, int K, int nbm)
{
  __shared__ __align__(16) u16 lds[2][2][256*64];   // [buf][A=0,B=1] 128 KB
  const int tid = threadIdx.x, wid = tid >> 6, lane = tid & 63;
  // T1: XCD swizzle (all grids %8==0), bm fastest
  const int nwg = gridDim.x;
  const int swz = (blockIdx.x & 7)*(nwg >> 3) + (blockIdx.x >> 3);
  const int bm = swz % nbm, bn = swz / nbm;
  const int wm = wid >> 2, wn = wid & 3;            // 2x4 waves, 128x64 each

  f32x4 acc[8][4] = {};

  // ---- staging (pre-swizzled global source; linear gload_lds dest) ----
  const int lrow = lane >> 3;                        // 0..7
  const int lkel = ((lane & 7) ^ lrow) * 8;          // swizzled k elem offset
  const u16* Abase = A  + (size_t)(bm*256)*K + lkel;
  const u16* Bbase = Bw + (size_t)(bn*256)*K + lkel;
  auto stageA = [&](int buf, int ha, int t) {
    const int r0 = ha*64 + 8*wid, r1 = 128 + ha*64 + 8*wid;
    const size_t ko = (size_t)t*64;
    gload_lds16(Abase + (size_t)(r0 + lrow)*K + ko, &lds[buf][0][r0*64]);
    gload_lds16(Abase + (size_t)(r1 + lrow)*K + ko, &lds[buf][0][r1*64]);
  };
  auto stageB = [&](int buf, int hb, int t) {
    const int r0 = hb*128 + 8*wid, r1 = hb*128 + 64 + 8*wid;
    const size_t ko = (size_t)t*64;
    gload_lds16(Bbase + (size_t)(r0 + lrow)*K + ko, &lds[buf][1][r0*64]);
    gload_lds16(Bbase + (size_t)(r1 + lrow)*K + ko, &lds[buf][1][r1*64]);
  };

  // ---- fragment reads (swizzled) ----
  const int frow = lane & 15, g = lane >> 4;
  auto ldsA = [&](int buf, int rowbase, int ks) -> bf16x8 {
    return *(const bf16x8*)&lds[buf][0][(rowbase + frow)*64 + ((ks*4 + g) ^ (lane & 7))*8];
  };
  auto ldsB = [&](int buf, int rowbase, int ks) -> bf16x8 {
    return *(const bf16x8*)&lds[buf][1][(rowbase + frow)*64 + ((ks*4 + g) ^ (lane & 7))*8];
  };

  bf16x8 bfrag[4][2];
  const int NT = K / 64;   // even (>=16 for all our shapes)

  // prologue: tile0 fully + tile1 {B-lo,B-hi,A-h1}; wait tile0 (3 HT in flight)
  stageB(0,0,0); stageB(0,1,0); stageA(0,0,0); stageA(0,1,0);
  stageB(1,0,1); stageB(1,1,1); stageA(1,0,1);
  asm volatile("s_waitcnt vmcnt(6)" ::: "memory");
  __builtin_amdgcn_s_barrier();
  asm volatile("" ::: "memory");

  for (int i = 0; i < NT/2 - 1; ++i) {
    const int t0 = 2*i;
    GPHASE(0, 0, stageA(1,1,t0+1), 0)   // complete tile t0+1
    GPHASE(0, 1, stageB(0,0,t0+2), 0)
    GPHASE(0, 2, stageB(0,1,t0+2), 0)
    GPHASE(0, 3, stageA(0,0,t0+2), 1)   // vmcnt(6): tile t0+1 landed
    GPHASE(1, 0, stageA(0,1,t0+2), 0)   // complete tile t0+2
    GPHASE(1, 1, stageB(1,0,t0+3), 0)
    GPHASE(1, 2, stageB(1,1,t0+3), 0)
    GPHASE(1, 3, stageA(1,0,t0+3), 1)   // vmcnt(6): tile t0+2 landed
  }
  // peeled last iteration (t0 = NT-2): no further stages; one vmcnt(0) drain
  GPHASE(0, 0, stageA(1,1,NT-1), 0)
  GPHASE(0, 1, ((void)0), 0)
  GPHASE(0, 2, ((void)0), 0)
  GPHASE(0, 3, ((void)0), 2)            // vmcnt(0): tile NT-1 landed
  GPHASE(1, 0, ((void)0), 0)
  GPHASE(1, 1, ((void)0), 0)
  GPHASE(1, 2, ((void)0), 0)
  GPHASE(1, 3, ((void)0), 0)

  // ---- epilogue ----
  if constexpr (EPI == 4) {
    // Fused RoPE + bf16 cvt + V transpose (R9-verified).
    const int hc = bn*4 + wn;                 // head-chunk 0..47
    const int which = hc >> 4, h = hc & 15;   // 0=q 1=k 2=v
    const int brow0 = bm*256 + wm*128 + g*4;
    const int b = brow0 >> 11;                // block-uniform
    const int bh = b*HEADS + h;
    if (which == 2) {
      #pragma unroll
      for (int mrep = 0; mrep < 8; ++mrep) {
        const int s = (brow0 + mrep*16) & (SEQ-1);
        #pragma unroll
        for (int n = 0; n < 4; ++n) {
          const int d = frow + n*16;
          ushort4 pk;
          pk.x = f2bf(acc[mrep][n][0]); pk.y = f2bf(acc[mrep][n][1]);
          pk.z = f2bf(acc[mrep][n][2]); pk.w = f2bf(acc[mrep][n][3]);
          *(ushort4*)&vto[((size_t)bh*64 + d)*SEQ + s] = pk;
        }
      }
    } else {
      u16* outb = (which == 0) ? qbo : kbo;
      const float qs = (which == 0) ? 0.125f : 1.f;   // fold 1/sqrt(HD)
      #pragma unroll
      for (int mrep = 0; mrep < 8; ++mrep) {
        #pragma unroll
        for (int rr = 0; rr < 4; ++rr) {
          const int s = (brow0 + mrep*16 + rr) & (SEQ-1);
          const float c0 = tab[s*64 + frow],      s0v = tab[s*64 + 32 + frow];
          const float c1 = tab[s*64 + 16 + frow], s1v = tab[s*64 + 48 + frow];
          const float x0 = acc[mrep][0][rr], x1 = acc[mrep][1][rr];
          const float x2 = acc[mrep][2][rr], x3 = acc[mrep][3][rr];
          u16* orow = outb + ((size_t)bh*SEQ + s)*64;
          orow[frow]      = f2bf((x0*c0 - x2*s0v)*qs);
          orow[frow + 32] = f2bf((x2*c0 + x0*s0v)*qs);
          orow[frow + 16] = f2bf((x1*c1 - x3*s1v)*qs);
          orow[frow + 48] = f2bf((x3*c1 + x1*s1v)*qs);
        }
      }
    }
  } else {
    const int row0 = bm*256 + wm*128 + g*4;
    const int col0 = bn*256 + wn*64 + frow;
    #pragma unroll
    for (int mrep = 0; mrep < 8; ++mrep) {
      #pragma unroll
      for (int n = 0; n < 4; ++n) {
        #pragma unroll
        for (int r = 0; r < 4; ++r) {
          const size_t idx = (size_t)(row0 + mrep*16 + r)*N + (col0 + n*16);
          const float v = acc[mrep][n][r];
          if constexpr (EPI == 0)      Cf[idx] = v;
          else if constexpr (EPI == 2) Cb[idx] = f2bf(v / (1.f + __expf(-v)));
        }
      }
    }
  }
}

// ---------------- elementwise / small kernels -------------------------------
__global__ void cvt_f32_bf16(const float* __restrict__ in, u16* __restrict__ out, int n4)
{
  const int i = blockIdx.x*256 + threadIdx.x;
  if (i >= n4) return;
  const float4 v = ((const float4*)in)[i];
  ushort4 o;
  o.x = f2bf(v.x); o.y = f2bf(v.y); o.z = f2bf(v.z); o.w = f2bf(v.w);
  ((ushort4*)out)[i] = o;
}

// all 4 per-layer weight conversions in one launch
__global__ void cvt_layer(const float* __restrict__ qw, const float* __restrict__ ow,
                          const float* __restrict__ f1, const float* __restrict__ f2,
                          u16* __restrict__ wq, u16* __restrict__ wo,
                          u16* __restrict__ w1, u16* __restrict__ w2)
{
  int i = blockIdx.x*256 + threadIdx.x;   // total 3.146M float4 groups
  const float* src; u16* dst;
  if (i < 786432)       { src = qw; dst = wq; }
  else if (i < 1048576) { src = ow; dst = wo; i -= 786432; }
  else if (i < 2097152) { src = f1; dst = w1; i -= 1048576; }
  else                  { src = f2; dst = w2; i -= 2097152; }
  const float4 v = ((const float4*)src)[i];
  ushort4 o;
  o.x = f2bf(v.x); o.y = f2bf(v.y); o.z = f2bf(v.z); o.w = f2bf(v.w);
  ((ushort4*)dst)[i] = o;
}

__global__ void embed_gather(const int* __restrict__ ids, const float* __restrict__ emb,
                             float* __restrict__ x)
{
  const int row = blockIdx.x, t = threadIdx.x;
  const int id = ids[row];
  ((float4*)(x + (size_t)row*DIM))[t] = ((const float4*)(emb + (size_t)id*DIM))[t];
}

__global__ __launch_bounds__(256)
void rmsnorm_bf16(const float* __restrict__ x, const float* __restrict__ scale,
                  u16* __restrict__ out)
{
  const int row = blockIdx.x, t = threadIdx.x;
  const float4 v = ((const float4*)(x + (size_t)row*DIM))[t];
  float ss = v.x*v.x + v.y*v.y + v.z*v.z + v.w*v.w;
  #pragma unroll
  for (int off = 32; off; off >>= 1) ss += __shfl_xor(ss, off);
  __shared__ float red[4];
  if ((t & 63) == 0) red[t >> 6] = ss;
  __syncthreads();
  const float tot = red[0] + red[1] + red[2] + red[3];
  const float r = rsqrtf(tot * (1.f/(float)DIM) + 1e-6f);
  const float4 sc = ((const float4*)scale)[t];
  ushort4 o;
  o.x = f2bf(v.x * r * sc.x);
  o.y = f2bf(v.y * r * sc.y);
  o.z = f2bf(v.z * r * sc.z);
  o.w = f2bf(v.w * r * sc.w);
  ((ushort4*)(out + (size_t)row*DIM))[t] = o;
}

__global__ void rope_table(float* __restrict__ tab)
{
  const int idx = blockIdx.x*256 + threadIdx.x;  // SEQ*32 threads
  const int s = idx >> 5, i = idx & 31;
  const float invf = powf(10000.f, -(float)i/32.f);
  const float f = (float)s * invf;
  tab[s*64 + i]      = cosf(f);
  tab[s*64 + 32 + i] = sinf(f);
}

// ---------------- MFMA flash attention: 64-key iterations (R13-exact) --------
__global__ __launch_bounds__(256, 4)
void attn_fwd(const u16* __restrict__ qb, const u16* __restrict__ kb,
              const u16* __restrict__ vt, u16* __restrict__ ctx)
{
  const int wid = threadIdx.x >> 6, lane = threadIdx.x & 63;
  const int bh = blockIdx.x >> 5, j = blockIdx.x & 31;
  const int qt = (wid == 0) ? j : (wid == 1) ? 63 - j : (wid == 2) ? 64 + j : 127 - j;
  const int q0 = qt * 16;
  const int g = lane >> 4, c15 = lane & 15;

  const u16* qbase = qb + (size_t)bh*SEQ*64;
  const u16* kbase = kb + (size_t)bh*SEQ*64;
  const u16* vtb   = vt + (size_t)bh*64*SEQ;

  const bf16x8 bQ0 = *(const bf16x8*)(qbase + (size_t)(q0 + c15)*64 + g*8);
  const bf16x8 bQ1 = *(const bf16x8*)(qbase + (size_t)(q0 + c15)*64 + 32 + g*8);

  f32x4 o[4] = {};
  float m = -INFINITY, lsum = 0.f;
  const int q_abs = q0 + c15;
  const int nt32 = (q0 >> 5) + 1;

  auto mk_aP = [&](const float* p) -> bf16x8 {
    const u32 pk00 = (u32)f2bf(p[0]) | ((u32)f2bf(p[1]) << 16);
    const u32 pk01 = (u32)f2bf(p[2]) | ((u32)f2bf(p[3]) << 16);
    const u32 pk10 = (u32)f2bf(p[4]) | ((u32)f2bf(p[5]) << 16);
    const u32 pk11 = (u32)f2bf(p[6]) | ((u32)f2bf(p[7]) << 16);
    u32 w[4];
    #pragma unroll
    for (int wi = 0; wi < 4; ++wi) {
      const int src = c15 | ((((g << 1) + (wi >> 1)) & 3) << 4);
      const u32 a0 = __shfl((wi & 1) ? pk01 : pk00, src);
      const u32 a1 = __shfl((wi & 1) ? pk11 : pk10, src);
      w[wi] = (g < 2) ? a0 : a1;
    }
    return __builtin_bit_cast(bf16x8, (u32x4){w[0], w[1], w[2], w[3]});
  };

  for (int t = 0; t < nt32; t += 2) {
    const int k0 = t*32;
    const bool haveB = (t + 1 < nt32);
    const bool diagA = (t     == nt32 - 1);
    const bool diagB = (t + 1 == nt32 - 1);

    const u16* kr0 = kbase + (size_t)(k0 + c15)*64 + g*8;
    const u16* kr1 = kbase + (size_t)(k0 + 16 + c15)*64 + g*8;
    const bf16x8 aK00 = *(const bf16x8*)(kr0);
    const bf16x8 aK01 = *(const bf16x8*)(kr0 + 32);
    const bf16x8 aK10 = *(const bf16x8*)(kr1);
    const bf16x8 aK11 = *(const bf16x8*)(kr1 + 32);
    bf16x8 aK20{}, aK21{}, aK30{}, aK31{};
    if (haveB) {
      const u16* kr2 = kbase + (size_t)(k0 + 32 + c15)*64 + g*8;
      const u16* kr3 = kbase + (size_t)(k0 + 48 + c15)*64 + g*8;
      aK20 = *(const bf16x8*)(kr2);
      aK21 = *(const bf16x8*)(kr2 + 32);
      aK30 = *(const bf16x8*)(kr3);
      aK31 = *(const bf16x8*)(kr3 + 32);
    }
    bf16x8 vvA[4];
    #pragma unroll
    for (int dh = 0; dh < 4; ++dh)
      vvA[dh] = *(const bf16x8*)(vtb + (size_t)(dh*16 + c15)*SEQ + k0 + g*8);

    const f32x4 z = {};
    f32x4 sc0 = __builtin_amdgcn_mfma_f32_16x16x32_bf16(aK00, bQ0, z, 0,0,0);
    sc0 = __builtin_amdgcn_mfma_f32_16x16x32_bf16(aK01, bQ1, sc0, 0,0,0);
    f32x4 sc1 = __builtin_amdgcn_mfma_f32_16x16x32_bf16(aK10, bQ0, z, 0,0,0);
    sc1 = __builtin_amdgcn_mfma_f32_16x16x32_bf16(aK11, bQ1, sc1, 0,0,0);
    f32x4 sc2 = z, sc3 = z;
    if (haveB) {
      sc2 = __builtin_amdgcn_mfma_f32_16x16x32_bf16(aK20, bQ0, z, 0,0,0);
      sc2 = __builtin_amdgcn_mfma_f32_16x16x32_bf16(aK21, bQ1, sc2, 0,0,0);
      sc3 = __builtin_amdgcn_mfma_f32_16x16x32_bf16(aK30, bQ0, z, 0,0,0);
      sc3 = __builtin_amdgcn_mfma_f32_16x16x32_bf16(aK31, bQ1, sc3, 0,0,0);
    }
    bf16x8 vvB[4] = {};
    if (haveB) {
      #pragma unroll
      for (int dh = 0; dh < 4; ++dh)
        vvB[dh] = *(const bf16x8*)(vtb + (size_t)(dh*16 + c15)*SEQ + k0 + 32 + g*8);
    }

    float s[16];
    if (diagA) {
      #pragma unroll
      for (int r = 0; r < 4; ++r) {
        s[r]   = (k0 + 4*g + r      > q_abs) ? -INFINITY : sc0[r];
        s[4+r] = (k0 + 16 + 4*g + r > q_abs) ? -INFINITY : sc1[r];
      }
    } else {
      #pragma unroll
      for (int r = 0; r < 4; ++r) { s[r] = sc0[r]; s[4+r] = sc1[r]; }
    }
    if (!haveB) {
      #pragma unroll
      for (int r = 0; r < 8; ++r) s[8+r] = -INFINITY;
    } else if (diagB) {
      #pragma unroll
      for (int r = 0; r < 4; ++r) {
        s[8+r]  = (k0 + 32 + 4*g + r > q_abs) ? -INFINITY : sc2[r];
        s[12+r] = (k0 + 48 + 4*g + r > q_abs) ? -INFINITY : sc3[r];
      }
    } else {
      #pragma unroll
      for (int r = 0; r < 4; ++r) { s[8+r] = sc2[r]; s[12+r] = sc3[r]; }
    }

    float tm = s[0];
    #pragma unroll
    for (int r = 1; r < 16; ++r) tm = fmaxf(tm, s[r]);
    tm = fmaxf(tm, __shfl_xor(tm, 16));
    tm = fmaxf(tm, __shfl_xor(tm, 32));

    if (!__all(tm <= m + 8.f)) {         // defer-max (T13)
      const float mnew = fmaxf(m, tm);
      const float corr = __expf(m - mnew);
      lsum *= corr;
      float corrq[4];
      #pragma unroll
      for (int r = 0; r < 4; ++r) corrq[r] = __shfl(corr, 4*g + r);
      #pragma unroll
      for (int dh = 0; dh < 4; ++dh)
        #pragma unroll
        for (int r = 0; r < 4; ++r) o[dh][r] *= corrq[r];
      m = mnew;
    }

    float p[16];
    #pragma unroll
    for (int r = 0; r < 16; ++r) p[r] = __expf(s[r] - m);
    float ps = 0.f;
    #pragma unroll
    for (int r = 0; r < 16; ++r) ps += p[r];
    ps += __shfl_xor(ps, 16);
    ps += __shfl_xor(ps, 32);
    lsum += ps;

    const bf16x8 aPA = mk_aP(&p[0]);
    #pragma unroll
    for (int dh = 0; dh < 4; ++dh)
      o[dh] = __builtin_amdgcn_mfma_f32_16x16x32_bf16(aPA, vvA[dh], o[dh], 0,0,0);
    if (haveB) {
      const bf16x8 aPB = mk_aP(&p[8]);
      #pragma unroll
      for (int dh = 0; dh < 4; ++dh)
        o[dh] = __builtin_amdgcn_mfma_f32_16x16x32_bf16(aPB, vvB[dh], o[dh], 0,0,0);
    }
  }

  float linv[4];
  #pragma unroll
  for (int r = 0; r < 4; ++r) linv[r] = 1.f / __shfl(lsum, 4*g + r);
  const int b = bh >> 4, h = bh & 15;
  #pragma unroll
  for (int r = 0; r < 4; ++r) {
    u16* crow = ctx + ((size_t)(b*SEQ + q0 + 4*g + r))*DIM + h*HD + c15;
    #pragma unroll
    for (int dh = 0; dh < 4; ++dh) crow[dh*16] = f2bf(o[dh][r] * linv[r]);
  }
}

// ---------------- host ------------------------------------------------------
extern "C" void kernel_launch(void* const* d_in, const int* in_sizes, int n_in,
                              void* d_out, int out_size, void* d_ws, size_t ws_size,
                              hipStream_t stream)
{
  const int*   ids   = (const int*)  d_in[0];
  const float* emb   = (const float*)d_in[1];
  const float* qkv_w = (const float*)d_in[2];
  const float* out_w = (const float*)d_in[3];
  const float* fc1_w = (const float*)d_in[4];
  const float* fc2_w = (const float*)d_in[5];
  const float* n1    = (const float*)d_in[6];
  const float* n2    = (const float*)d_in[7];
  const float* nf    = (const float*)d_in[8];
  const float* lm_w  = (const float*)d_in[9];
  float* logits = (float*)d_out;

  char* ws = (char*)d_ws;
  size_t off = 0;
  auto walloc = [&](size_t bytes) -> void* {
    void* p = ws + off;
    off += (bytes + 255) & ~(size_t)255;
    return p;
  };
  float* x     = (float*)walloc((size_t)ROWS*DIM*4);        // residual stream (f32)
  u16*   hbf   = (u16*)  walloc((size_t)ROWS*DIM*2);        // normed activ (bf16)
  u16*   ctxbf = (u16*)  walloc((size_t)ROWS*DIM*2);        // attn out (bf16)
  u16*   gbf   = (u16*)  walloc((size_t)ROWS*FF*2);         // silu(fc1) (bf16)
  u16*   wq    = (u16*)  walloc((size_t)3*DIM*DIM*2);
  u16*   wo    = (u16*)  walloc((size_t)DIM*DIM*2);
  u16*   w1    = (u16*)  walloc((size_t)FF*DIM*2);
  u16*   w2    = (u16*)  walloc((size_t)DIM*FF*2);
  float* tab   = (float*)walloc((size_t)SEQ*64*4);
  float* fpart = (float*)walloc((size_t)2*ROWS*DIM*4);      // split-K partials
  // bf16 Q/K/Vt alias gbf (25.2MB <= 33.6MB); lifetimes disjoint.
  u16* qbuf = (u16*)gbf;
  u16* kbuf = qbuf + (size_t)ROWS*DIM;
  u16* vtbuf= kbuf + (size_t)ROWS*DIM;
  // lm_w bf16 (65.5MB) aliases ctxbf..w2 (67.1MB) — all dead at LM-head time.
  u16* wlm = (u16*)ctxbf;

  rope_table<<<SEQ*32/256, 256, 0, stream>>>(tab);
  embed_gather<<<ROWS, 256, 0, stream>>>(ids, emb, x);
  rmsnorm_bf16<<<ROWS, 256, 0, stream>>>(x, n1, hbf);   // l=0 pre-attn norm

  for (int l = 0; l < LAYERS; ++l) {
    cvt_layer<<<3145728/256, 256, 0, stream>>>(
        qkv_w + (size_t)l*3*DIM*DIM, out_w + (size_t)l*DIM*DIM,
        fc1_w + (size_t)l*FF*DIM,    fc2_w + (size_t)l*DIM*FF,
        wq, wo, w1, w2);

    gemm_nt_256<4><<<(3*DIM/256)*(ROWS/256), 512, 0, stream>>>(
        hbf, wq, nullptr, nullptr, qbuf, kbuf, vtbuf, tab, ROWS, 3*DIM, DIM, ROWS/256);
    attn_fwd<<<BATCH*HEADS*(SEQ/64), 256, 0, stream>>>(qbuf, kbuf, vtbuf, ctxbf);
    // out-proj split-K=2 -> partials; fused reduce + residual + n2-norm
    gemm_nt<5><<<dim3(DIM/BN, ROWS/BM, 2), 256, 0, stream>>>(ctxbf, wo, fpart, nullptr, ROWS, DIM, DIM, DIM/2);
    residual_add2_norm<<<ROWS, 256, 0, stream>>>(x, fpart, fpart + (size_t)ROWS*DIM,
                                                 n2 + l*DIM, hbf);

    gemm_nt_256<2><<<(FF/256)*(ROWS/256), 512, 0, stream>>>(
        hbf, w1, nullptr, gbf, nullptr, nullptr, nullptr, nullptr, ROWS, FF, DIM, ROWS/256);
    // fc2 split-K=2 -> partials; fused reduce + residual + next-norm (n1 or nf)
    gemm_nt<5><<<dim3(DIM/BN, ROWS/BM, 2), 256, 0, stream>>>(gbf, w2, fpart, nullptr, ROWS, DIM, FF, FF/2);
    const float* nxt = (l < LAYERS-1) ? (n1 + (size_t)(l+1)*DIM) : nf;
    residual_add2_norm<<<ROWS, 256, 0, stream>>>(x, fpart, fpart + (size_t)ROWS*DIM,
                                                 nxt, hbf);
  }

  cvt_f32_bf16<<<VOCAB*DIM/4/256, 256, 0, stream>>>(lm_w, wlm, VOCAB*DIM/4);
  gemm_nt_256<0><<<(VOCAB/256)*(ROWS/256), 512, 0, stream>>>(
      hbf, wlm, logits, nullptr, nullptr, nullptr, nullptr, nullptr, ROWS, VOCAB, DIM, ROWS/256);
}